// Round 13
// baseline (39.757 us; speedup 1.0000x reference)
//
#include <hip/hip_runtime.h>
#include <hip/hip_fp16.h>

#define NI 65536
#define NO 65536
#define NW 32
#define NB 32

typedef float  fx4 __attribute__((ext_vector_type(4)));
typedef float  fx2 __attribute__((ext_vector_type(2)));
typedef int    ix4 __attribute__((ext_vector_type(4)));
typedef uint   ux4 __attribute__((ext_vector_type(4)));
typedef ushort sx4 __attribute__((ext_vector_type(4)));

// T[i] = 128B record (64 ushorts): [0:32) = x column i (fp16, b=0..31),
//                                  [32:64) = fp16(fw*fm) row i (w=0..31).
// fmb[i] bit w = (fm[i][w] != 0).

// ---- kernel 1: build T + fmb ----
__global__ __launch_bounds__(256) void dsm_prep(
    const float* __restrict__ x, const float* __restrict__ fw,
    const float* __restrict__ fm, ushort* __restrict__ T16,
    uint* __restrict__ fmb)
{
    __shared__ float tile[32][33];
    __shared__ uint  lfmb[32];
    const int tid = threadIdx.x;
    const int tx = tid & 31, ty = tid >> 5;
    const int i0 = blockIdx.x * 32;

    if (tid < 32) lfmb[tid] = 0;
#pragma unroll
    for (int r = 0; r < 4; ++r) {
        const int b = ty + 8 * r;
        tile[b][tx] = __builtin_nontemporal_load(&x[(size_t)b * NI + i0 + tx]);
    }
    __syncthreads();
#pragma unroll
    for (int r = 0; r < 4; ++r) {
        const int ii = ty + 8 * r;
        T16[(size_t)(i0 + ii) * 64 + tx] =
            __half_as_ushort(__float2half(tile[tx][ii]));
    }
    // fw*fm -> fp16 into record upper half; fm bitmap
    const size_t base = (size_t)blockIdx.x * 1024 + (size_t)tid * 4;
    const int row = i0 + (tid >> 3);
    const int w0  = (tid & 7) * 4;
    const fx4 a = __builtin_nontemporal_load((const fx4*)(fw + base));
    const fx4 m = __builtin_nontemporal_load((const fx4*)(fm + base));
    sx4 h;
    h.x = __half_as_ushort(__float2half(a.x * m.x));
    h.y = __half_as_ushort(__float2half(a.y * m.y));
    h.z = __half_as_ushort(__float2half(a.z * m.z));
    h.w = __half_as_ushort(__float2half(a.w * m.w));
    *(sx4*)(T16 + (size_t)row * 64 + 32 + w0) = h;

    const uint bits = (m.x != 0.f ? 1u : 0u) | (m.y != 0.f ? 2u : 0u)
                    | (m.z != 0.f ? 4u : 0u) | (m.w != 0.f ? 8u : 0u);
    atomicOr(&lfmb[tid >> 3], bits << w0);
    __syncthreads();
    if (tid < 32) fmb[blockIdx.x * 32 + tid] = lfmb[tid];
}

// ---- kernel 2 (fused): wave = 16 o-rows x 4 lanes (16B/lane) — r11 layout.
//      Phase A: filter + ballot compaction + survivor-only s-gather from the
//      T-record upper half (folds s into key AND prefetches phase B's line).
//      Phase B: ONE 16B x-load per survivor + pk-FMA. Block = 64 o's. ----
__global__ __launch_bounds__(256) void dsm_fused(
    const int*    __restrict__ om,
    const float*  __restrict__ rm,
    const ushort* __restrict__ T16,    // [NI] 128B records
    const uint*   __restrict__ fmb,    // [NI] bitmap
    float* __restrict__ out)           // [NB][NO]
{
    __shared__ uint sp[4][576];        // per-wave 16 rows, stride 36
    const int tid  = threadIdx.x;
    const int wave = tid >> 6;
    const int lane = tid & 63;
    const int row  = lane >> 2;        // o sub-index within wave (0..15)
    const int c    = lane & 3;         // 16B chunk: b = 8c..8c+7
    const int o_block = blockIdx.x * 64;
    const int o_wave  = o_block + wave * 16;

#pragma unroll
    for (int k = lane; k < 576; k += 64) sp[wave][k] = 0;

    // ---- phase A: filter + s-gather (line prefetch) + compaction ----
    int cnt = 0;
    {
        const size_t ebase = (size_t)o_wave * NW + (size_t)lane * 8;
        const ix4 iv0 = __builtin_nontemporal_load((const ix4*)(om + ebase));
        const ix4 iv1 = __builtin_nontemporal_load((const ix4*)(om + ebase + 4));
        const fx4 rv0 = __builtin_nontemporal_load((const fx4*)(rm + ebase));
        const fx4 rv1 = __builtin_nontemporal_load((const fx4*)(rm + ebase + 4));
        const int w0 = c * 8;
        uint  ii[8]; float rr[8]; uint fb[8];
#pragma unroll
        for (int j = 0; j < 8; ++j) {
            ii[j] = (uint)((j < 4) ? iv0[j] : iv1[j - 4]) & 0xffffu;
            rr[j] = (j < 4) ? rv0[j] : rv1[j - 4];
        }
#pragma unroll
        for (int j = 0; j < 8; ++j) fb[j] = fmb[ii[j]];

        uint keep[8], key[8];
#pragma unroll
        for (int j = 0; j < 8; ++j) {
            keep[j] = (rr[j] != 0.0f) & ((fb[j] >> (w0 + j)) & 1u);
            key[j] = ii[j] << 16;
            if (keep[j])               // survivor-only 2B gather; prefetches line
                key[j] |= (uint)T16[ii[j] * 64u + 32u + (uint)(w0 + j)];
        }
        const unsigned long long rowmask  = 0xFull << (row * 4);
        const unsigned long long beforeme = (1ull << lane) - 1ull;
#pragma unroll
        for (int j = 0; j < 8; ++j) {
            const unsigned long long bl = __ballot(keep[j] != 0u);
            const int pos = cnt + __popcll(bl & rowmask & beforeme);
            if (keep[j]) sp[wave][row * 36 + pos] = key[j];
            cnt += __popcll(bl & rowmask);
        }
    }
    __syncthreads();

    // ---- phase B: one 16B load per survivor, pk-FMA, 2x-unrolled MLP ----
    fx2 a0 = {0.f, 0.f}, a1 = {0.f, 0.f}, a2 = {0.f, 0.f}, a3 = {0.f, 0.f};
    {
        const uint* spw = &sp[wave][row * 36];
        const int nw = (cnt + 3) & ~3;       // uniform within 4-lane group
#pragma unroll 2
        for (int t = 0; t < nw; t += 4) {
            const ux4 k4 = *(const ux4*)(spw + t);   // ds_read_b128 broadcast
#pragma unroll
            for (int j = 0; j < 4; ++j) {
                const uint p = k4[j];
                const uint i = p >> 16;
                const float sv = __half2float(__ushort_as_half((ushort)(p & 0xffffu)));
                const fx2 s2 = {sv, sv};
                const ux4 xv = *(const ux4*)(T16 + i * 64u + (uint)c * 8u); // 16B
#pragma unroll
                for (int k = 0; k < 4; ++k) {
                    fx2 xk;
                    xk.x = __half2float(__ushort_as_half((ushort)(xv[k] & 0xffffu)));
                    xk.y = __half2float(__ushort_as_half((ushort)(xv[k] >> 16)));
                    if (k == 0) a0 = s2 * xk + a0;
                    else if (k == 1) a1 = s2 * xk + a1;
                    else if (k == 2) a2 = s2 * xk + a2;
                    else a3 = s2 * xk + a3;
                }
            }
        }
    }
    __syncthreads();                   // all waves done with their sp segments

    // ---- epilogue: tile (32 b x 64 o-cols, stride 65) then coalesced store ----
    float* tile = (float*)sp;          // 2304 uints >= 32*65
    const int ocol = wave * 16 + row;
    tile[(c * 8 + 0) * 65 + ocol] = a0.x;
    tile[(c * 8 + 1) * 65 + ocol] = a0.y;
    tile[(c * 8 + 2) * 65 + ocol] = a1.x;
    tile[(c * 8 + 3) * 65 + ocol] = a1.y;
    tile[(c * 8 + 4) * 65 + ocol] = a2.x;
    tile[(c * 8 + 5) * 65 + ocol] = a2.y;
    tile[(c * 8 + 6) * 65 + ocol] = a3.x;
    tile[(c * 8 + 7) * 65 + ocol] = a3.y;
    __syncthreads();
    {
        const int col = tid & 63;
#pragma unroll
        for (int r = 0; r < 8; ++r) {
            const int b = (tid >> 6) + 4 * r;
            __builtin_nontemporal_store(tile[b * 65 + col],
                                        &out[(size_t)b * NO + o_block + col]);
        }
    }
}

// ---- fallback (no workspace): direct fp32, half-wave per o ----
__global__ __launch_bounds__(256) void dsm_fallback(
    const float* __restrict__ x, const float* __restrict__ fw,
    const float* __restrict__ fm, const int* __restrict__ om,
    const float* __restrict__ rm, float* __restrict__ out)
{
    const int tid = threadIdx.x;
    const int l = tid & 31, hw = tid >> 5;
    const int o = blockIdx.x * 8 + hw;
    const int i_l = om[(size_t)o * NW + l];
    const float s_l = fw[(size_t)i_l * NW + l] * fm[(size_t)i_l * NW + l]
                    * rm[(size_t)o * NW + l];
    float acc = 0.f;
#pragma unroll
    for (int w = 0; w < NW; ++w) {
        const int   i = __shfl(i_l, w, 32);
        const float s = __shfl(s_l, w, 32);
        acc = fmaf(s, x[(size_t)l * NI + i], acc);
    }
    out[(size_t)l * NO + o] = acc;
}

extern "C" void kernel_launch(void* const* d_in, const int* in_sizes, int n_in,
                              void* d_out, int out_size, void* d_ws, size_t ws_size,
                              hipStream_t stream) {
    const float* x  = (const float*)d_in[0];
    const float* fw = (const float*)d_in[1];
    const float* fm = (const float*)d_in[2];
    const int*   om = (const int*)d_in[3];
    const float* rm = (const float*)d_in[4];
    float* out = (float*)d_out;

    const size_t needT  = (size_t)NI * 64 * sizeof(ushort);  // 8 MB
    const size_t needFB = (size_t)NI * sizeof(uint);         // 256 KB

    if (ws_size >= needT + needFB) {
        ushort* T16 = (ushort*)d_ws;
        uint*   fmb = (uint*)((char*)d_ws + needT);
        dsm_prep<<<dim3(NI / 32), 256, 0, stream>>>(x, fw, fm, T16, fmb);
        dsm_fused<<<dim3(NO / 64), 256, 0, stream>>>(om, rm, T16, fmb, out);
    } else {
        dsm_fallback<<<dim3(NO / 8), 256, 0, stream>>>(x, fw, fm, om, rm, out);
    }
}

// Round 14
// 37.103 us; speedup vs baseline: 1.0715x; 1.0715x over previous
//
#include <hip/hip_runtime.h>
#include <hip/hip_fp16.h>

#define NI 65536
#define NO 65536
#define NW 32
#define NB 32

typedef float  fx4 __attribute__((ext_vector_type(4)));
typedef float  fx2 __attribute__((ext_vector_type(2)));
typedef int    ix4 __attribute__((ext_vector_type(4)));
typedef uint   ux4 __attribute__((ext_vector_type(4)));
typedef ushort sx4 __attribute__((ext_vector_type(4)));

// T[i] = 128B record (64 ushorts): [0:32) = x column i (fp16, b=0..31),
//                                  [32:64) = fp16(fw*fm) row i (w=0..31).
// fmb[i] bit w = (fm[i][w] != 0).

// ---- kernel 1: build T + fmb ----
__global__ __launch_bounds__(256) void dsm_prep(
    const float* __restrict__ x, const float* __restrict__ fw,
    const float* __restrict__ fm, ushort* __restrict__ T16,
    uint* __restrict__ fmb)
{
    __shared__ float tile[32][33];
    __shared__ uint  lfmb[32];
    const int tid = threadIdx.x;
    const int tx = tid & 31, ty = tid >> 5;
    const int i0 = blockIdx.x * 32;

    if (tid < 32) lfmb[tid] = 0;
#pragma unroll
    for (int r = 0; r < 4; ++r) {
        const int b = ty + 8 * r;
        tile[b][tx] = __builtin_nontemporal_load(&x[(size_t)b * NI + i0 + tx]);
    }
    __syncthreads();
#pragma unroll
    for (int r = 0; r < 4; ++r) {
        const int ii = ty + 8 * r;
        T16[(size_t)(i0 + ii) * 64 + tx] =
            __half_as_ushort(__float2half(tile[tx][ii]));
    }
    // fw*fm -> fp16 into record upper half; fm bitmap
    const size_t base = (size_t)blockIdx.x * 1024 + (size_t)tid * 4;
    const int row = i0 + (tid >> 3);
    const int w0  = (tid & 7) * 4;
    const fx4 a = __builtin_nontemporal_load((const fx4*)(fw + base));
    const fx4 m = __builtin_nontemporal_load((const fx4*)(fm + base));
    sx4 h;
    h.x = __half_as_ushort(__float2half(a.x * m.x));
    h.y = __half_as_ushort(__float2half(a.y * m.y));
    h.z = __half_as_ushort(__float2half(a.z * m.z));
    h.w = __half_as_ushort(__float2half(a.w * m.w));
    *(sx4*)(T16 + (size_t)row * 64 + 32 + w0) = h;

    const uint bits = (m.x != 0.f ? 1u : 0u) | (m.y != 0.f ? 2u : 0u)
                    | (m.z != 0.f ? 4u : 0u) | (m.w != 0.f ? 8u : 0u);
    atomicOr(&lfmb[tid >> 3], bits << w0);
    __syncthreads();
    if (tid < 32) fmb[blockIdx.x * 32 + tid] = lfmb[tid];
}

// ---- kernel 2 (fused): block = 32 o's, 4 waves. Each o-row's 32 w-entries
//      are SPLIT across two waves (w<16 / w>=16): wave = rowset*2 + half.
//      Wave layout = 16 rows x 4 lanes (16B x-chunk/lane) — r11's shape.
//      Phase A: filter via fmb only + ballot compaction (4 entries/lane).
//      Phase B: one 128B record line per survivor (s + 16B x), pk-FMA.
//      Epilogue: half-0 writes tile, half-1 adds, coalesced store.
//      Grid = 2048 blocks -> 8192 waves = 32/CU (2x r11). ----
__global__ __launch_bounds__(256) void dsm_fused(
    const int*    __restrict__ om,
    const float*  __restrict__ rm,
    const ushort* __restrict__ T16,    // [NI] 128B records
    const uint*   __restrict__ fmb,    // [NI] bitmap
    float* __restrict__ out)           // [NB][NO]
{
    __shared__ uint sp[4][320];        // per-wave 16 rows, stride 20
    const int tid    = threadIdx.x;
    const int wave   = tid >> 6;
    const int lane   = tid & 63;
    const int half   = wave & 1;       // w-half: 0 -> w<16, 1 -> w>=16
    const int rowset = wave >> 1;      // o sub-block (0..1)
    const int row    = lane >> 2;      // o within rowset (0..15)
    const int c      = lane & 3;       // 16B chunk: b = 8c..8c+7
    const int o_block = blockIdx.x * 32;
    const int o_mine  = o_block + rowset * 16 + row;

#pragma unroll
    for (int k = lane; k < 320; k += 64) sp[wave][k] = 0;

    // ---- phase A: filter + ballot compaction (4 entries/lane) ----
    int cnt = 0;
    {
        const int wbase = half * 16 + c * 4;          // entry j -> w = wbase+j
        const size_t ebase = (size_t)o_mine * NW + wbase;
        const ix4 iv = __builtin_nontemporal_load((const ix4*)(om + ebase));
        const fx4 rv = __builtin_nontemporal_load((const fx4*)(rm + ebase));
        uint fb[4];
#pragma unroll
        for (int j = 0; j < 4; ++j) fb[j] = fmb[(uint)iv[j] & 0xffffu];

        const unsigned long long rowmask  = 0xFull << (row * 4);
        const unsigned long long beforeme = (1ull << lane) - 1ull;
#pragma unroll
        for (int j = 0; j < 4; ++j) {
            const uint i = (uint)iv[j] & 0xffffu;
            const uint w = (uint)(wbase + j);
            const uint keep = (rv[j] != 0.0f) & ((fb[j] >> w) & 1u);
            const unsigned long long bl = __ballot(keep != 0u);
            const int pos = cnt + __popcll(bl & rowmask & beforeme);
            if (keep) sp[wave][row * 20 + pos] = (i << 16) | 0x20u | w;
            cnt += __popcll(bl & rowmask);
        }
    }
    __syncthreads();

    // ---- phase B: one 128B line per survivor (s + x same line) ----
    fx2 a0 = {0.f, 0.f}, a1 = {0.f, 0.f}, a2 = {0.f, 0.f}, a3 = {0.f, 0.f};
    {
        const uint* spw = &sp[wave][row * 20];
        const int nw = (cnt + 3) & ~3;       // uniform within 4-lane group
#pragma unroll 2
        for (int t = 0; t < nw; t += 4) {
            const ux4 k4 = *(const ux4*)(spw + t);   // ds_read_b128 broadcast
#pragma unroll
            for (int j = 0; j < 4; ++j) {
                const uint p = k4[j];
                const uint i = p >> 16;
                const uint w = p & 31u;
                float sv = __half2float(__ushort_as_half(T16[i * 64u + 32u + w]));
                sv = (p & 0x20u) ? sv : 0.0f;        // pad slots contribute 0
                const fx2 s2 = {sv, sv};
                const ux4 xv = *(const ux4*)(T16 + i * 64u + (uint)c * 8u); // 16B
#pragma unroll
                for (int k = 0; k < 4; ++k) {
                    fx2 xk;
                    xk.x = __half2float(__ushort_as_half((ushort)(xv[k] & 0xffffu)));
                    xk.y = __half2float(__ushort_as_half((ushort)(xv[k] >> 16)));
                    if (k == 0) a0 = s2 * xk + a0;
                    else if (k == 1) a1 = s2 * xk + a1;
                    else if (k == 2) a2 = s2 * xk + a2;
                    else a3 = s2 * xk + a3;
                }
            }
        }
    }
    __syncthreads();                   // all waves done with their sp segments

    // ---- epilogue: half-0 writes tile, half-1 accumulates, then store ----
    float* tile = (float*)sp;          // 1280 uints >= 32*33 floats
    const int ocol = rowset * 16 + row;
    if (half == 0) {
        tile[(c * 8 + 0) * 33 + ocol] = a0.x;
        tile[(c * 8 + 1) * 33 + ocol] = a0.y;
        tile[(c * 8 + 2) * 33 + ocol] = a1.x;
        tile[(c * 8 + 3) * 33 + ocol] = a1.y;
        tile[(c * 8 + 4) * 33 + ocol] = a2.x;
        tile[(c * 8 + 5) * 33 + ocol] = a2.y;
        tile[(c * 8 + 6) * 33 + ocol] = a3.x;
        tile[(c * 8 + 7) * 33 + ocol] = a3.y;
    }
    __syncthreads();
    if (half == 1) {
        tile[(c * 8 + 0) * 33 + ocol] += a0.x;
        tile[(c * 8 + 1) * 33 + ocol] += a0.y;
        tile[(c * 8 + 2) * 33 + ocol] += a1.x;
        tile[(c * 8 + 3) * 33 + ocol] += a1.y;
        tile[(c * 8 + 4) * 33 + ocol] += a2.x;
        tile[(c * 8 + 5) * 33 + ocol] += a2.y;
        tile[(c * 8 + 6) * 33 + ocol] += a3.x;
        tile[(c * 8 + 7) * 33 + ocol] += a3.y;
    }
    __syncthreads();
#pragma unroll
    for (int r = 0; r < 4; ++r) {
        const int b = (tid >> 5) + 8 * r;
        __builtin_nontemporal_store(tile[b * 33 + (tid & 31)],
                                    &out[(size_t)b * NO + o_block + (tid & 31)]);
    }
}

// ---- fallback (no workspace): direct fp32, half-wave per o ----
__global__ __launch_bounds__(256) void dsm_fallback(
    const float* __restrict__ x, const float* __restrict__ fw,
    const float* __restrict__ fm, const int* __restrict__ om,
    const float* __restrict__ rm, float* __restrict__ out)
{
    const int tid = threadIdx.x;
    const int l = tid & 31, hw = tid >> 5;
    const int o = blockIdx.x * 8 + hw;
    const int i_l = om[(size_t)o * NW + l];
    const float s_l = fw[(size_t)i_l * NW + l] * fm[(size_t)i_l * NW + l]
                    * rm[(size_t)o * NW + l];
    float acc = 0.f;
#pragma unroll
    for (int w = 0; w < NW; ++w) {
        const int   i = __shfl(i_l, w, 32);
        const float s = __shfl(s_l, w, 32);
        acc = fmaf(s, x[(size_t)l * NI + i], acc);
    }
    out[(size_t)l * NO + o] = acc;
}

extern "C" void kernel_launch(void* const* d_in, const int* in_sizes, int n_in,
                              void* d_out, int out_size, void* d_ws, size_t ws_size,
                              hipStream_t stream) {
    const float* x  = (const float*)d_in[0];
    const float* fw = (const float*)d_in[1];
    const float* fm = (const float*)d_in[2];
    const int*   om = (const int*)d_in[3];
    const float* rm = (const float*)d_in[4];
    float* out = (float*)d_out;

    const size_t needT  = (size_t)NI * 64 * sizeof(ushort);  // 8 MB
    const size_t needFB = (size_t)NI * sizeof(uint);         // 256 KB

    if (ws_size >= needT + needFB) {
        ushort* T16 = (ushort*)d_ws;
        uint*   fmb = (uint*)((char*)d_ws + needT);
        dsm_prep<<<dim3(NI / 32), 256, 0, stream>>>(x, fw, fm, T16, fmb);
        dsm_fused<<<dim3(NO / 32), 256, 0, stream>>>(om, rm, T16, fmb, out);
    } else {
        dsm_fallback<<<dim3(NO / 8), 256, 0, stream>>>(x, fw, fm, om, rm, out);
    }
}